// Round 5
// baseline (591.298 us; speedup 1.0000x reference)
//
#include <hip/hip_runtime.h>
#include <cstdint>
#include <cstddef>

typedef __bf16 bf16;
typedef __bf16 bf16x2 __attribute__((ext_vector_type(2)));
typedef __bf16 bf16x8 __attribute__((ext_vector_type(8)));
typedef float  f32x4  __attribute__((ext_vector_type(4)));

#define INVF_C 0.20762050593046014f   // log2(10000)/64

// global -> LDS async copy, 16B per lane. LDS base must be wave-uniform;
// HW scatters lane i at base + 16*i. (m97-verified pattern.)
__device__ __forceinline__ void async_copy16(const void* g, void* l)
{
    auto gp = (__attribute__((address_space(1))) const void*)(reinterpret_cast<uintptr_t>(g));
    auto lp = (__attribute__((address_space(3))) void*)(uint32_t)(reinterpret_cast<uintptr_t>(l));
    __builtin_amdgcn_global_load_lds(gp, lp, 16, 0, 0);
}

// ---------------------------------------------------------------------------
// elementwise fp32 -> bf16 cast, 4 elems/thread, n % 4 == 0
// ---------------------------------------------------------------------------
__global__ void cast_to_bf16(const float* __restrict__ in, bf16* __restrict__ out, int n)
{
    const int i = (blockIdx.x * 256 + threadIdx.x) * 4;
    if (i < n) {
        const float4 v = *(const float4*)(in + i);
        out[i]     = (bf16)v.x;
        out[i + 1] = (bf16)v.y;
        out[i + 2] = (bf16)v.z;
        out[i + 3] = (bf16)v.w;
    }
}

// ---------------------------------------------------------------------------
// fused transpose + cast: out[c*R + r] = (bf16)in[r*C + c]; in is RxC fp32.
// 64x64 tile, 256 threads; float4 loads, bf16x2 stores (G13: scalar 2B
// stores were half-BW). R, C multiples of 64. grid (C/64, R/64).
// LDS bank check: loads (row+4c+k)%32 covers each bank 2x; stores read
// (2t+cc)%32 2-way -> all free (m136).
// ---------------------------------------------------------------------------
__global__ __launch_bounds__(256)
void transpose_cast(const float* __restrict__ in, bf16* __restrict__ out,
                    int R, int Ccols)
{
    __shared__ float tile[64][65];
    const int c0 = blockIdx.x * 64;
    const int r0 = blockIdx.y * 64;
    const int tid = threadIdx.x;
    const int lr = tid >> 4;
    const int lc = (tid & 15) * 4;
#pragma unroll
    for (int i = 0; i < 4; ++i) {
        const int row = i * 16 + lr;
        const float4 v = *(const float4*)(in + (size_t)(r0 + row) * Ccols + c0 + lc);
        tile[row][lc]     = v.x;
        tile[row][lc + 1] = v.y;
        tile[row][lc + 2] = v.z;
        tile[row][lc + 3] = v.w;
    }
    __syncthreads();
    const int rr  = (tid & 31) * 2;
    const int cc0 = tid >> 5;
#pragma unroll
    for (int i = 0; i < 8; ++i) {
        const int cc = i * 8 + cc0;
        bf16x2 p = { (bf16)tile[rr][cc], (bf16)tile[rr + 1][cc] };
        *(bf16x2*)(out + (size_t)(c0 + cc) * R + r0 + rr) = p;
    }
}

// ---------------------------------------------------------------------------
// XCD-aware block swizzle (T1): chunked remap so each XCD gets a contiguous
// run of tiles -> A-panels stay resident in that XCD's private L2.
// Requires nwg % 8 == 0 (all our GEMM grids: 1024/1024/512/512).
// ---------------------------------------------------------------------------
__device__ __forceinline__ void xcd_tile(int& m0, int& n0)
{
    const int bid = blockIdx.y * gridDim.x + blockIdx.x;
    const int cpx = (gridDim.x * gridDim.y) >> 3;
    const int swz = (bid & 7) * cpx + (bid >> 3);
    m0 = (swz / gridDim.x) * 128;
    n0 = (swz % gridDim.x) * 128;
}

// ---------------------------------------------------------------------------
// Shared GEMM main loop (m97 structure): 128x128 tile, BK=64, 4 waves 2x2,
// global_load_lds width-16 staging into unpadded LDS. Verified round 0-2.
// ---------------------------------------------------------------------------
__device__ __forceinline__ void gemm_core(const bf16* __restrict__ A,
                                          const bf16* __restrict__ Bt,
                                          int K, int m0, int n0,
                                          bf16* As, bf16* Bs,
                                          f32x4 (&acc)[4][4])
{
    const int tid  = threadIdx.x;
    const int wave = tid >> 6;
    const int lane = tid & 63;
    const int quad = lane >> 4;
    const int l15  = lane & 15;
    const int wm   = (wave >> 1) * 64;
    const int wn   = (wave & 1) * 64;

    // staging: wave w covers rows [w*32, w*32+32) in 4 issues of 8 rows;
    // lane l -> row l>>3, col chunk (l&7)*8 (matches lane*16B LDS scatter)
    const int srow = lane >> 3;
    const int scol = (lane & 7) * 8;
    const bf16* Ab = A  + (size_t)(m0 + wave * 32 + srow) * K + scol;
    const bf16* Bb = Bt + (size_t)(n0 + wave * 32 + srow) * K + scol;
    bf16* AsW = &As[(wave * 32) * 64];
    bf16* BsW = &Bs[(wave * 32) * 64];

    for (int k0 = 0; k0 < K; k0 += 64) {
        __syncthreads();   // previous tile fully consumed
#pragma unroll
        for (int i = 0; i < 4; ++i) {
            async_copy16(Ab + (size_t)(i * 8) * K + k0, AsW + i * 8 * 64);
            async_copy16(Bb + (size_t)(i * 8) * K + k0, BsW + i * 8 * 64);
        }
        __syncthreads();   // drains vmcnt(0) -> staged data visible
#pragma unroll
        for (int ks = 0; ks < 2; ++ks) {
            bf16x8 af[4], bfr[4];
#pragma unroll
            for (int i = 0; i < 4; ++i)
                af[i] = *(const bf16x8*)&As[(wm + i * 16 + l15) * 64 + ks * 32 + quad * 8];
#pragma unroll
            for (int j = 0; j < 4; ++j)
                bfr[j] = *(const bf16x8*)&Bs[(wn + j * 16 + l15) * 64 + ks * 32 + quad * 8];
#pragma unroll
            for (int i = 0; i < 4; ++i)
#pragma unroll
                for (int j = 0; j < 4; ++j)
                    acc[i][j] = __builtin_amdgcn_mfma_f32_16x16x32_bf16(af[i], bfr[j], acc[i][j], 0, 0, 0);
        }
    }
}

// ---------------------------------------------------------------------------
// Generic C[M,N] = A @ Bt^T + bias; dual fp32/bf16 epilogue (final GEMM).
// ---------------------------------------------------------------------------
__global__ __launch_bounds__(256, 2)
void gemm_bt(const bf16* __restrict__ A, const bf16* __restrict__ Bt,
             const float* __restrict__ bias, float* __restrict__ C,
             bf16* __restrict__ Cb, int M, int N, int K)
{
    __shared__ bf16 As[128 * 64];
    __shared__ bf16 Bs[128 * 64];
    int m0, n0;
    xcd_tile(m0, n0);
    f32x4 acc[4][4] = {};
    gemm_core(A, Bt, K, m0, n0, As, Bs, acc);

    const int tid  = threadIdx.x;
    const int wave = tid >> 6;
    const int lane = tid & 63;
    const int quad = lane >> 4;
    const int l15  = lane & 15;
    const int wm   = (wave >> 1) * 64;
    const int wn   = (wave & 1) * 64;

    // C/D layout: col = lane&15, row = quad*4 + r (verified m89/m91)
#pragma unroll
    for (int j = 0; j < 4; ++j) {
        const int col = n0 + wn + j * 16 + l15;
        const float bv = bias[col];
#pragma unroll
        for (int i = 0; i < 4; ++i) {
            const int row = m0 + wm + i * 16 + quad * 4;
#pragma unroll
            for (int r = 0; r < 4; ++r) {
                const float v = acc[i][j][r] + bv;
                if (C)  C [(size_t)(row + r) * N + col] = v;
                if (Cb) Cb[(size_t)(row + r) * N + col] = (bf16)v;
            }
        }
    }
}

// ---------------------------------------------------------------------------
// Batched GEMM #1: A=hb (4096x2048), B = [W_DKV^T | W_KR^T | W_DQ^T]
// stacked as WtAll (4096 x 2048). N=4096 -> 1024 blocks (full device).
// Section epilogues: cols [0,512) -> cKV fp32+bf16; [512,2560) -> krc fp32;
// [2560,4096) -> cQ bf16. Section boundaries are multiples of 128.
// ---------------------------------------------------------------------------
__global__ __launch_bounds__(256, 2)
void gemm_batch1(const bf16* __restrict__ A, const bf16* __restrict__ WtAll,
                 const float* __restrict__ bDKV, const float* __restrict__ bKR,
                 const float* __restrict__ bDQ,
                 float* __restrict__ cKV_f, bf16* __restrict__ cKVb,
                 float* __restrict__ krc_f, bf16* __restrict__ cQ)
{
    __shared__ bf16 As[128 * 64];
    __shared__ bf16 Bs[128 * 64];
    int m0, n0;
    xcd_tile(m0, n0);
    f32x4 acc[4][4] = {};
    gemm_core(A, WtAll, 2048, m0, n0, As, Bs, acc);

    const int tid  = threadIdx.x;
    const int wave = tid >> 6;
    const int lane = tid & 63;
    const int quad = lane >> 4;
    const int l15  = lane & 15;
    const int wm   = (wave >> 1) * 64;
    const int wn   = (wave & 1) * 64;

    if (n0 < 512) {
#pragma unroll
        for (int j = 0; j < 4; ++j) {
            const int col = n0 + wn + j * 16 + l15;
            const float bv = bDKV[col];
#pragma unroll
            for (int i = 0; i < 4; ++i) {
                const int row = m0 + wm + i * 16 + quad * 4;
#pragma unroll
                for (int r = 0; r < 4; ++r) {
                    const float v = acc[i][j][r] + bv;
                    cKV_f[(size_t)(row + r) * 512 + col] = v;
                    cKVb [(size_t)(row + r) * 512 + col] = (bf16)v;
                }
            }
        }
    } else if (n0 < 2560) {
#pragma unroll
        for (int j = 0; j < 4; ++j) {
            const int col = n0 + wn + j * 16 + l15;
            const int cl  = col - 512;
            const float bv = bKR[cl];
#pragma unroll
            for (int i = 0; i < 4; ++i) {
                const int row = m0 + wm + i * 16 + quad * 4;
#pragma unroll
                for (int r = 0; r < 4; ++r)
                    krc_f[(size_t)(row + r) * 2048 + cl] = acc[i][j][r] + bv;
            }
        }
    } else {
#pragma unroll
        for (int j = 0; j < 4; ++j) {
            const int col = n0 + wn + j * 16 + l15;
            const int cl  = col - 2560;
            const float bv = bDQ[cl];
#pragma unroll
            for (int i = 0; i < 4; ++i) {
                const int row = m0 + wm + i * 16 + quad * 4;
#pragma unroll
                for (int r = 0; r < 4; ++r)
                    cQ[(size_t)(row + r) * 1536 + cl] = (bf16)(acc[i][j][r] + bv);
            }
        }
    }
}

// ---------------------------------------------------------------------------
// Batched GEMM #4+5: A=cKVb (4096x512), B = [W_UK^T | W_UV^T] (4096x512).
// Cols [0,2048) -> kC; [2048,4096) -> vC. Both bf16.
// ---------------------------------------------------------------------------
__global__ __launch_bounds__(256, 2)
void gemm_batch45(const bf16* __restrict__ A, const bf16* __restrict__ Wt45,
                  const float* __restrict__ bUK, const float* __restrict__ bUV,
                  bf16* __restrict__ kC, bf16* __restrict__ vC)
{
    __shared__ bf16 As[128 * 64];
    __shared__ bf16 Bs[128 * 64];
    int m0, n0;
    xcd_tile(m0, n0);
    f32x4 acc[4][4] = {};
    gemm_core(A, Wt45, 512, m0, n0, As, Bs, acc);

    const int tid  = threadIdx.x;
    const int wave = tid >> 6;
    const int lane = tid & 63;
    const int quad = lane >> 4;
    const int l15  = lane & 15;
    const int wm   = (wave >> 1) * 64;
    const int wn   = (wave & 1) * 64;

    const bool isK = (n0 < 2048);
    bf16* outp = isK ? kC : vC;
    const float* bp = isK ? bUK : bUV;
    const int base = isK ? 0 : 2048;
#pragma unroll
    for (int j = 0; j < 4; ++j) {
        const int col = n0 + wn + j * 16 + l15;
        const int cl  = col - base;
        const float bv = bp[cl];
#pragma unroll
        for (int i = 0; i < 4; ++i) {
            const int row = m0 + wm + i * 16 + quad * 4;
#pragma unroll
            for (int r = 0; r < 4; ++r)
                outp[(size_t)(row + r) * 2048 + cl] = (bf16)(acc[i][j][r] + bv);
        }
    }
}

// ---------------------------------------------------------------------------
// qC GEMM with fused RoPE epilogue: writes qC = A@Wt+b (bf16) AND
// qR = rope(qC fp32) (bf16). Pair partner col^1 lives in lane l15^1.
// __sincosf (hw v_sin/v_cos): sincosf's Payne-Hanek slow path used scratch
// -> 845 MB WRITE_SIZE (round-3 post-mortem). Angle err ~2e-4 rad << bf16.
// ---------------------------------------------------------------------------
__global__ __launch_bounds__(256, 2)
void gemm_q_rope(const bf16* __restrict__ A, const bf16* __restrict__ Bt,
                 const float* __restrict__ bias,
                 bf16* __restrict__ qC, bf16* __restrict__ qR)
{
    __shared__ bf16 As[128 * 64];
    __shared__ bf16 Bs[128 * 64];
    int m0, n0;
    xcd_tile(m0, n0);
    f32x4 acc[4][4] = {};
    gemm_core(A, Bt, 1536, m0, n0, As, Bs, acc);

    const int tid  = threadIdx.x;
    const int wave = tid >> 6;
    const int lane = tid & 63;
    const int quad = lane >> 4;
    const int l15  = lane & 15;
    const int wm   = (wave >> 1) * 64;
    const int wn   = (wave & 1) * 64;
    const int odd  = l15 & 1;

#pragma unroll
    for (int j = 0; j < 4; ++j) {
        const int col = n0 + wn + j * 16 + l15;
        const float bv = bias[col];
        const float freq = exp2f(-(float)((col & 127) >> 1) * INVF_C);
#pragma unroll
        for (int i = 0; i < 4; ++i) {
            const int rowb = m0 + wm + i * 16 + quad * 4;
#pragma unroll
            for (int r = 0; r < 4; ++r) {
                const int row = rowb + r;
                const float v = acc[i][j][r] + bv;
                qC[(size_t)row * 2048 + col] = (bf16)v;
                const float vp = __shfl_xor(v, 1, 64);
                const float x1 = odd ? vp : v;
                const float x2 = odd ? v  : vp;
                const float ang = (float)(row & 2047) * freq;
                float sn, cs;
                __sincosf(ang, &sn, &cs);
                qR[(size_t)row * 2048 + col] =
                    (bf16)(odd ? (x1 * sn + x2 * cs) : (x1 * cs - x2 * sn));
            }
        }
    }
}

// vC (B*S, H*128) bf16 -> vT (B*H, 128, S). grid (S/32, 128/32, 32), block (32,8)
__global__ void transpose_v(const bf16* __restrict__ vC, bf16* __restrict__ vT)
{
    __shared__ bf16 tile[32][33];
    const int bh = blockIdx.z, b = bh >> 4, h = bh & 15;
    const int s0 = blockIdx.x * 32, d0 = blockIdx.y * 32;
    const int tx = threadIdx.x, ty = threadIdx.y;
    for (int i = ty; i < 32; i += 8)
        tile[i][tx] = vC[((size_t)(b * 2048 + s0 + i)) * 2048 + h * 128 + d0 + tx];
    __syncthreads();
    for (int i = ty; i < 32; i += 8)
        vT[((size_t)(bh * 128 + d0 + i)) * 2048 + s0 + tx] = tile[tx][i];
}

// ---------------------------------------------------------------------------
// per-head interleaved RoPE (kR path), layout (B*S, H*128), fp32 input.
// __sincosf: no scratch slow path (round-3 post-mortem).
// ---------------------------------------------------------------------------
__global__ void rope_heads_f(const float* __restrict__ in, bf16* __restrict__ out)
{
    const int idx = blockIdx.x * 256 + threadIdx.x;     // 2*2048*16*64 total
    const int j = idx & 63;
    const int h = (idx >> 6) & 15;
    const int s = (idx >> 10) & 2047;
    const int b = idx >> 21;
    const size_t src = ((size_t)(b * 2048 + s)) * 2048 + h * 128 + 2 * j;
    const float x1 = in[src], x2 = in[src + 1];
    const float ang = (float)s * exp2f(-(float)j * INVF_C);
    float sn, cs;
    __sincosf(ang, &sn, &cs);
    out[src]     = (bf16)(x1 * cs - x2 * sn);
    out[src + 1] = (bf16)(x1 * sn + x2 * cs);
}

// ---------------------------------------------------------------------------
// Flash attention, causal. Split operands, all bf16:
//   qC,qR,kC,kR : (B*S, H*128) row-major;  Vt : (B*H, 128, S).
// BQ=128 (8 waves x 16 q-rows, wave-local softmax), BKV=64.
// Grid (bh=32, y=16): 512 blocks, 2/CU -> all co-resident.
// Balance remap: co-resident pair (y, y+8) -> q-tiles (2y, 15-2y) -> constant
// 34 KV-tile-units per CU (verified round 2: 159 -> 138 us).
// launch_bounds(512,2): 2 blocks/CU = what LDS allows; (512,4) caused a
// 64-VGPR cap and spills (round-1 post-mortem).
// T5 setprio around MFMA clusters (catalog: attn +4-7%, m191).
// T13 defer-max: skip O-rescale when max growth <= 8 (P bounded by e^8,
// fine in bf16; active tiles never have fully-masked rows since wq, kk0
// are both multiples of 16).
// LDS: Ks 64x264 + Vs 128x72 + Ps 128x72 = 70656 B.
// ---------------------------------------------------------------------------
__global__ __launch_bounds__(512, 2)
void mla_attn(const bf16* __restrict__ qCp, const bf16* __restrict__ qRp,
              const bf16* __restrict__ kCp, const bf16* __restrict__ kRp,
              const bf16* __restrict__ Vt, bf16* __restrict__ ctx)
{
    __shared__ bf16 Ks[64 * 264];
    __shared__ bf16 Vs[128 * 72];
    __shared__ bf16 Ps[128 * 72];
    const int bh   = blockIdx.x;
    const int b    = bh >> 4, hh = bh & 15;
    const int yq   = blockIdx.y;
    const int qt   = (yq < 8) ? (2 * yq) : (31 - 2 * yq);   // balance remap
    const int q0   = qt * 128;
    const int tid  = threadIdx.x;
    const int wave = tid >> 6;
    const int lane = tid & 63;
    const int quad = lane >> 4;
    const int l15  = lane & 15;
    const int wq   = q0 + wave * 16;       // wave's first q row

    // Q fragments resident (A-operand: m=lane&15, k=quad*8+j).
    bf16x8 qf[8];
    {
        const size_t qoff = ((size_t)(b * 2048 + wq + l15)) * 2048
                          + hh * 128 + quad * 8;
#pragma unroll
        for (int ks = 0; ks < 4; ++ks) {
            qf[ks]     = *(const bf16x8*)(qCp + qoff + ks * 32);
            qf[4 + ks] = *(const bf16x8*)(qRp + qoff + ks * 32);
        }
    }

    float mstate[4], lstate[4];
    f32x4 o[8];
#pragma unroll
    for (int r = 0; r < 4; ++r) { mstate[r] = -1e30f; lstate[r] = 0.0f; }
#pragma unroll
    for (int dt = 0; dt < 8; ++dt) { f32x4 z = {0.f, 0.f, 0.f, 0.f}; o[dt] = z; }

    const int krow = tid >> 4, kcol = (tid & 15) * 8;   // K staging (512 thr)
    const int vsr  = tid >> 3, vsc  = (tid & 7) * 8;    // V staging

    const int ntiles = 2 * qt + 2;
    for (int t = 0; t < ntiles; ++t) {
        const int kk0 = t * 64;
        __syncthreads();
#pragma unroll
        for (int it = 0; it < 2; ++it) {   // Ks: 64 rows x (128 | 128)
            const int row = it * 32 + krow;
            const size_t g = ((size_t)(b * 2048 + kk0 + row)) * 2048 + hh * 128 + kcol;
            *(bf16x8*)&Ks[row * 264 + kcol]       = *(const bf16x8*)(kCp + g);
            *(bf16x8*)&Ks[row * 264 + 128 + kcol] = *(const bf16x8*)(kRp + g);
        }
#pragma unroll
        for (int it = 0; it < 2; ++it) {   // Vs: 128 d-rows x 64 kk
            const int d = it * 64 + vsr;
            *(bf16x8*)&Vs[d * 72 + vsc] =
                *(const bf16x8*)(Vt + ((size_t)(bh * 128 + d)) * 2048 + kk0 + vsc);
        }
        __syncthreads();

        if (kk0 <= wq + 15) {   // wave-uniform: tile not fully masked
            f32x4 sc[4] = {};
            __builtin_amdgcn_s_setprio(1);
#pragma unroll
            for (int ks = 0; ks < 8; ++ks)
#pragma unroll
                for (int j = 0; j < 4; ++j) {
                    bf16x8 kf = *(const bf16x8*)&Ks[(j * 16 + l15) * 264 + ks * 32 + quad * 8];
                    sc[j] = __builtin_amdgcn_mfma_f32_16x16x32_bf16(qf[ks], kf, sc[j], 0, 0, 0);
                }
            __builtin_amdgcn_s_setprio(0);

            const bool diag = (kk0 + 63 > wq);
            float rowmax[4] = {-1e30f, -1e30f, -1e30f, -1e30f};
#pragma unroll
            for (int j = 0; j < 4; ++j) {
                const int kkcol = kk0 + j * 16 + l15;
#pragma unroll
                for (int r = 0; r < 4; ++r) {
                    float s = sc[j][r] * 0.0625f;             // 1/sqrt(256)
                    if (diag && (kkcol > wq + quad * 4 + r)) s = -1e30f;
                    sc[j][r] = s;
                    rowmax[r] = fmaxf(rowmax[r], s);
                }
            }
#pragma unroll
            for (int r = 0; r < 4; ++r) {  // reduce across the 16 col-lanes
                float v = rowmax[r];
                v = fmaxf(v, __shfl_xor(v, 1, 64));
                v = fmaxf(v, __shfl_xor(v, 2, 64));
                v = fmaxf(v, __shfl_xor(v, 4, 64));
                v = fmaxf(v, __shfl_xor(v, 8, 64));
                rowmax[r] = v;
            }
            // T13 defer-max: only rescale when a row's max grew by > 8.
            const bool resc = __any((rowmax[0] > mstate[0] + 8.0f) |
                                    (rowmax[1] > mstate[1] + 8.0f) |
                                    (rowmax[2] > mstate[2] + 8.0f) |
                                    (rowmax[3] > mstate[3] + 8.0f));
            if (resc) {
                float alpha[4];
#pragma unroll
                for (int r = 0; r < 4; ++r) {
                    const float mnew = fmaxf(mstate[r], rowmax[r]);
                    alpha[r] = __expf(mstate[r] - mnew);
                    mstate[r] = mnew;
                    lstate[r] *= alpha[r];
                }
#pragma unroll
                for (int dt = 0; dt < 8; ++dt)
#pragma unroll
                    for (int r = 0; r < 4; ++r)
                        o[dt][r] *= alpha[r];
            }
            float rowsum[4] = {0.f, 0.f, 0.f, 0.f};
#pragma unroll
            for (int j = 0; j < 4; ++j)
#pragma unroll
                for (int r = 0; r < 4; ++r) {
                    const float p = __expf(sc[j][r] - mstate[r]);
                    sc[j][r] = p;
                    rowsum[r] += p;
                }
#pragma unroll
            for (int r = 0; r < 4; ++r) {
                float v = rowsum[r];
                v += __shfl_xor(v, 1, 64);
                v += __shfl_xor(v, 2, 64);
                v += __shfl_xor(v, 4, 64);
                v += __shfl_xor(v, 8, 64);
                lstate[r] += v;
            }
            // P: C-layout -> LDS -> A-operand layout (verified, m120)
#pragma unroll
            for (int j = 0; j < 4; ++j)
#pragma unroll
                for (int r = 0; r < 4; ++r)
                    Ps[(wave * 16 + quad * 4 + r) * 72 + j * 16 + l15] = (bf16)sc[j][r];
            __builtin_amdgcn_s_setprio(1);
#pragma unroll
            for (int ks2 = 0; ks2 < 2; ++ks2) {
                bf16x8 pf = *(const bf16x8*)&Ps[(wave * 16 + l15) * 72 + ks2 * 32 + quad * 8];
#pragma unroll
                for (int dt = 0; dt < 8; ++dt) {
                    bf16x8 vf = *(const bf16x8*)&Vs[(dt * 16 + l15) * 72 + ks2 * 32 + quad * 8];
                    o[dt] = __builtin_amdgcn_mfma_f32_16x16x32_bf16(pf, vf, o[dt], 0, 0, 0);
                }
            }
            __builtin_amdgcn_s_setprio(0);
        }
    }

    float inv_l[4];
#pragma unroll
    for (int r = 0; r < 4; ++r) inv_l[r] = 1.0f / lstate[r];
#pragma unroll
    for (int dt = 0; dt < 8; ++dt) {
        const int d = dt * 16 + l15;
#pragma unroll
        for (int r = 0; r < 4; ++r) {
            const int q = wq + quad * 4 + r;
            ctx[((size_t)(b * 2048 + q)) * 2048 + hh * 128 + d] = (bf16)(o[dt][r] * inv_l[r]);
        }
    }
}

// ---------------------------------------------------------------------------
extern "C" void kernel_launch(void* const* d_in, const int* in_sizes, int n_in,
                              void* d_out, int out_size, void* d_ws, size_t ws_size,
                              hipStream_t stream)
{
    const float* h     = (const float*)d_in[0];
    const float* W_DKV = (const float*)d_in[1];
    const float* b_DKV = (const float*)d_in[2];
    const float* W_UK  = (const float*)d_in[3];
    const float* b_UK  = (const float*)d_in[4];
    const float* W_UV  = (const float*)d_in[5];
    const float* b_UV  = (const float*)d_in[6];
    const float* W_DQ  = (const float*)d_in[7];
    const float* b_DQ  = (const float*)d_in[8];
    const float* W_UQ  = (const float*)d_in[9];
    const float* b_UQ  = (const float*)d_in[10];
    const float* W_KR  = (const float*)d_in[11];
    const float* b_KR  = (const float*)d_in[12];
    const float* W_O   = (const float*)d_in[13];
    const float* b_O   = (const float*)d_in[14];

    float* out   = (float*)d_out;             // (4096, 2048)  output 0, fp32
    float* cKV_f = out + (size_t)8388608;     // (4096, 512)   output 1
    float* krc_f = out + (size_t)10485760;    // (4096, 2048)  output 2

    // out-proper (33.5 MB) is dead until the final GEMM -> park qC + qR
    // there; both consumed by mla_attn before the final GEMM overwrites.
    bf16* qC = (bf16*)d_out;                  // (B*S, H*128)
    bf16* qR = (bf16*)d_out + 8388608;        // (B*S, H*128)

    // ws (bf16 elements), lifetimes:
    //  hb    @0        8.4M  cast -> batch1; then reused as kR
    //  cKVb  @8.4M     2.1M  batch1 -> batch45
    //  cQ    @10.5M    6.3M  batch1 -> gemm_q
    //  WtAll @16.8M    8.4M  tc(DKV|KR|DQ) -> batch1; tc(UK|UV) -> batch45;
    //                        tc(UQ) -> gemm_q; then vT -> attn; then tc(WO)
    //  kC    @25.2M    8.4M  batch45 -> attn
    //  vC    @33.6M    8.4M  batch45 -> transpose_v; then ctx (attn -> final)
    bf16* ws    = (bf16*)d_ws;
    bf16* hb    = ws + 0;
    bf16* cKVb  = ws + 8388608;
    bf16* cQ    = ws + 10485760;
    bf16* WtAll = ws + 16777216;
    bf16* kC    = ws + 25165824;
    bf16* vC    = ws + 33554432;
    bf16* kR    = hb;              // hb dead after batch1
    bf16* vT    = WtAll;           // WtAll free between gemm_q and tc(WO)
    bf16* ctx   = vC;              // vC dead after transpose_v

    dim3 tb(32, 8);

    cast_to_bf16<<<8192, 256, 0, stream>>>(h, hb, 8388608);

    // WtAll rows: [0,512)=W_DKV^T, [512,2560)=W_KR^T, [2560,4096)=W_DQ^T
    transpose_cast<<<dim3(8, 32),  256, 0, stream>>>(W_DKV, WtAll,           2048, 512);
    transpose_cast<<<dim3(32, 32), 256, 0, stream>>>(W_KR,  WtAll + 1048576, 2048, 2048);
    transpose_cast<<<dim3(24, 32), 256, 0, stream>>>(W_DQ,  WtAll + 5242880, 2048, 1536);

    gemm_batch1<<<dim3(32, 32), 256, 0, stream>>>(hb, WtAll, b_DKV, b_KR, b_DQ,
                                                  cKV_f, cKVb, krc_f, cQ);
    // hb dead from here
    rope_heads_f<<<16384, 256, 0, stream>>>(krc_f, kR);

    // Wt45 rows: [0,2048)=W_UK^T, [2048,4096)=W_UV^T (K=512)
    transpose_cast<<<dim3(32, 8), 256, 0, stream>>>(W_UK, WtAll,           512, 2048);
    transpose_cast<<<dim3(32, 8), 256, 0, stream>>>(W_UV, WtAll + 1048576, 512, 2048);
    gemm_batch45<<<dim3(32, 32), 256, 0, stream>>>(cKVb, WtAll, b_UK, b_UV, kC, vC);

    transpose_cast<<<dim3(32, 24), 256, 0, stream>>>(W_UQ, WtAll, 1536, 2048);
    gemm_q_rope<<<dim3(16, 32), 256, 0, stream>>>(cQ, WtAll, b_UQ, qC, qR);

    transpose_v<<<dim3(64, 4, 32), tb, 0, stream>>>(vC, vT);   // vC consumed

    mla_attn<<<dim3(32, 16), 512, 0, stream>>>(qC, qR, kC, kR, vT, ctx);

    transpose_cast<<<dim3(32, 32), 256, 0, stream>>>(W_O, WtAll, 2048, 2048);
    gemm_bt<<<dim3(16, 32), 256, 0, stream>>>(ctx, WtAll, b_O, out, nullptr, 4096, 2048, 2048);
}

// Round 6
// 533.350 us; speedup vs baseline: 1.1086x; 1.1086x over previous
//
#include <hip/hip_runtime.h>
#include <cstdint>
#include <cstddef>

typedef __bf16 bf16;
typedef __bf16 bf16x8 __attribute__((ext_vector_type(8)));
typedef float  f32x4  __attribute__((ext_vector_type(4)));

#define INVF_C 0.20762050593046014f   // log2(10000)/64

// global -> LDS async copy, 16B per lane. LDS base must be wave-uniform;
// HW scatters lane i at base + 16*i. (m97-verified pattern.)
__device__ __forceinline__ void async_copy16(const void* g, void* l)
{
    auto gp = (__attribute__((address_space(1))) const void*)(reinterpret_cast<uintptr_t>(g));
    auto lp = (__attribute__((address_space(3))) void*)(uint32_t)(reinterpret_cast<uintptr_t>(l));
    __builtin_amdgcn_global_load_lds(gp, lp, 16, 0, 0);
}

// ---------------------------------------------------------------------------
// elementwise fp32 -> bf16 cast, 4 elems/thread, n % 4 == 0
// ---------------------------------------------------------------------------
__global__ void cast_to_bf16(const float* __restrict__ in, bf16* __restrict__ out, int n)
{
    const int i = (blockIdx.x * 256 + threadIdx.x) * 4;
    if (i < n) {
        const float4 v = *(const float4*)(in + i);
        out[i]     = (bf16)v.x;
        out[i + 1] = (bf16)v.y;
        out[i + 2] = (bf16)v.z;
        out[i + 3] = (bf16)v.w;
    }
}

// ---------------------------------------------------------------------------
// fused transpose + cast: out[c*R + r] = (bf16)in[r*C + c]; in is RxC fp32.
// grid (C/32, R/32), block (32,8).  (round-4 version; the round-5 64x64
// rewrite was part of an unattributed regression -> reverted)
// ---------------------------------------------------------------------------
__global__ void transpose_cast(const float* __restrict__ in, bf16* __restrict__ out,
                               int R, int Ccols)
{
    __shared__ float tile[32][33];
    const int c0 = blockIdx.x * 32;
    const int r0 = blockIdx.y * 32;
    const int tx = threadIdx.x, ty = threadIdx.y;
    for (int i = ty; i < 32; i += 8)
        tile[i][tx] = in[(size_t)(r0 + i) * Ccols + c0 + tx];
    __syncthreads();
    for (int i = ty; i < 32; i += 8)
        out[(size_t)(c0 + i) * R + r0 + tx] = (bf16)tile[tx][i];
}

// ---------------------------------------------------------------------------
// Shared GEMM main loop (m97 structure): 128x128 tile, BK=64, 4 waves 2x2,
// global_load_lds width-16 staging into unpadded LDS. Verified round 0-4.
// No XCD swizzle: all operands are L3-resident; round-5 composite with
// swizzle regressed (m160: swizzle costs ~2% when L3-fit).
// ---------------------------------------------------------------------------
__device__ __forceinline__ void gemm_core(const bf16* __restrict__ A,
                                          const bf16* __restrict__ Bt,
                                          int K, int m0, int n0,
                                          bf16* As, bf16* Bs,
                                          f32x4 (&acc)[4][4])
{
    const int tid  = threadIdx.x;
    const int wave = tid >> 6;
    const int lane = tid & 63;
    const int quad = lane >> 4;
    const int l15  = lane & 15;
    const int wm   = (wave >> 1) * 64;
    const int wn   = (wave & 1) * 64;

    // staging: wave w covers rows [w*32, w*32+32) in 4 issues of 8 rows;
    // lane l -> row l>>3, col chunk (l&7)*8 (matches lane*16B LDS scatter)
    const int srow = lane >> 3;
    const int scol = (lane & 7) * 8;
    const bf16* Ab = A  + (size_t)(m0 + wave * 32 + srow) * K + scol;
    const bf16* Bb = Bt + (size_t)(n0 + wave * 32 + srow) * K + scol;
    bf16* AsW = &As[(wave * 32) * 64];
    bf16* BsW = &Bs[(wave * 32) * 64];

    for (int k0 = 0; k0 < K; k0 += 64) {
        __syncthreads();   // previous tile fully consumed
#pragma unroll
        for (int i = 0; i < 4; ++i) {
            async_copy16(Ab + (size_t)(i * 8) * K + k0, AsW + i * 8 * 64);
            async_copy16(Bb + (size_t)(i * 8) * K + k0, BsW + i * 8 * 64);
        }
        __syncthreads();   // drains vmcnt(0) -> staged data visible
#pragma unroll
        for (int ks = 0; ks < 2; ++ks) {
            bf16x8 af[4], bfr[4];
#pragma unroll
            for (int i = 0; i < 4; ++i)
                af[i] = *(const bf16x8*)&As[(wm + i * 16 + l15) * 64 + ks * 32 + quad * 8];
#pragma unroll
            for (int j = 0; j < 4; ++j)
                bfr[j] = *(const bf16x8*)&Bs[(wn + j * 16 + l15) * 64 + ks * 32 + quad * 8];
#pragma unroll
            for (int i = 0; i < 4; ++i)
#pragma unroll
                for (int j = 0; j < 4; ++j)
                    acc[i][j] = __builtin_amdgcn_mfma_f32_16x16x32_bf16(af[i], bfr[j], acc[i][j], 0, 0, 0);
        }
    }
}

// ---------------------------------------------------------------------------
// Generic C[M,N] = A @ Bt^T + bias; dual fp32/bf16 epilogue (final GEMM).
// ---------------------------------------------------------------------------
__global__ __launch_bounds__(256, 2)
void gemm_bt(const bf16* __restrict__ A, const bf16* __restrict__ Bt,
             const float* __restrict__ bias, float* __restrict__ C,
             bf16* __restrict__ Cb, int M, int N, int K)
{
    __shared__ bf16 As[128 * 64];
    __shared__ bf16 Bs[128 * 64];
    const int m0 = blockIdx.y * 128;
    const int n0 = blockIdx.x * 128;
    f32x4 acc[4][4] = {};
    gemm_core(A, Bt, K, m0, n0, As, Bs, acc);

    const int tid  = threadIdx.x;
    const int wave = tid >> 6;
    const int lane = tid & 63;
    const int quad = lane >> 4;
    const int l15  = lane & 15;
    const int wm   = (wave >> 1) * 64;
    const int wn   = (wave & 1) * 64;

    // C/D layout: col = lane&15, row = quad*4 + r (verified m89/m91)
#pragma unroll
    for (int j = 0; j < 4; ++j) {
        const int col = n0 + wn + j * 16 + l15;
        const float bv = bias[col];
#pragma unroll
        for (int i = 0; i < 4; ++i) {
            const int row = m0 + wm + i * 16 + quad * 4;
#pragma unroll
            for (int r = 0; r < 4; ++r) {
                const float v = acc[i][j][r] + bv;
                if (C)  C [(size_t)(row + r) * N + col] = v;
                if (Cb) Cb[(size_t)(row + r) * N + col] = (bf16)v;
            }
        }
    }
}

// ---------------------------------------------------------------------------
// Batched GEMM #1: A=hb (4096x2048), B = [W_DKV^T | W_KR^T | W_DQ^T]
// stacked as WtAll (4096 x 2048). N=4096 -> 1024 blocks (full device).
// Section epilogues: cols [0,512) -> cKV fp32+bf16; [512,2560) -> krc fp32;
// [2560,4096) -> cQ bf16. Section boundaries are multiples of 128.
// ---------------------------------------------------------------------------
__global__ __launch_bounds__(256, 2)
void gemm_batch1(const bf16* __restrict__ A, const bf16* __restrict__ WtAll,
                 const float* __restrict__ bDKV, const float* __restrict__ bKR,
                 const float* __restrict__ bDQ,
                 float* __restrict__ cKV_f, bf16* __restrict__ cKVb,
                 float* __restrict__ krc_f, bf16* __restrict__ cQ)
{
    __shared__ bf16 As[128 * 64];
    __shared__ bf16 Bs[128 * 64];
    const int m0 = blockIdx.y * 128;
    const int n0 = blockIdx.x * 128;
    f32x4 acc[4][4] = {};
    gemm_core(A, WtAll, 2048, m0, n0, As, Bs, acc);

    const int tid  = threadIdx.x;
    const int wave = tid >> 6;
    const int lane = tid & 63;
    const int quad = lane >> 4;
    const int l15  = lane & 15;
    const int wm   = (wave >> 1) * 64;
    const int wn   = (wave & 1) * 64;

    if (n0 < 512) {
#pragma unroll
        for (int j = 0; j < 4; ++j) {
            const int col = n0 + wn + j * 16 + l15;
            const float bv = bDKV[col];
#pragma unroll
            for (int i = 0; i < 4; ++i) {
                const int row = m0 + wm + i * 16 + quad * 4;
#pragma unroll
                for (int r = 0; r < 4; ++r) {
                    const float v = acc[i][j][r] + bv;
                    cKV_f[(size_t)(row + r) * 512 + col] = v;
                    cKVb [(size_t)(row + r) * 512 + col] = (bf16)v;
                }
            }
        }
    } else if (n0 < 2560) {
#pragma unroll
        for (int j = 0; j < 4; ++j) {
            const int col = n0 + wn + j * 16 + l15;
            const int cl  = col - 512;
            const float bv = bKR[cl];
#pragma unroll
            for (int i = 0; i < 4; ++i) {
                const int row = m0 + wm + i * 16 + quad * 4;
#pragma unroll
                for (int r = 0; r < 4; ++r)
                    krc_f[(size_t)(row + r) * 2048 + cl] = acc[i][j][r] + bv;
            }
        }
    } else {
#pragma unroll
        for (int j = 0; j < 4; ++j) {
            const int col = n0 + wn + j * 16 + l15;
            const int cl  = col - 2560;
            const float bv = bDQ[cl];
#pragma unroll
            for (int i = 0; i < 4; ++i) {
                const int row = m0 + wm + i * 16 + quad * 4;
#pragma unroll
                for (int r = 0; r < 4; ++r)
                    cQ[(size_t)(row + r) * 1536 + cl] = (bf16)(acc[i][j][r] + bv);
            }
        }
    }
}

// ---------------------------------------------------------------------------
// Batched GEMM #4+5: A=cKVb (4096x512), B = [W_UK^T | W_UV^T] (4096x512).
// Cols [0,2048) -> kC; [2048,4096) -> vC. Both bf16.
// ---------------------------------------------------------------------------
__global__ __launch_bounds__(256, 2)
void gemm_batch45(const bf16* __restrict__ A, const bf16* __restrict__ Wt45,
                  const float* __restrict__ bUK, const float* __restrict__ bUV,
                  bf16* __restrict__ kC, bf16* __restrict__ vC)
{
    __shared__ bf16 As[128 * 64];
    __shared__ bf16 Bs[128 * 64];
    const int m0 = blockIdx.y * 128;
    const int n0 = blockIdx.x * 128;
    f32x4 acc[4][4] = {};
    gemm_core(A, Wt45, 512, m0, n0, As, Bs, acc);

    const int tid  = threadIdx.x;
    const int wave = tid >> 6;
    const int lane = tid & 63;
    const int quad = lane >> 4;
    const int l15  = lane & 15;
    const int wm   = (wave >> 1) * 64;
    const int wn   = (wave & 1) * 64;

    const bool isK = (n0 < 2048);
    bf16* outp = isK ? kC : vC;
    const float* bp = isK ? bUK : bUV;
    const int base = isK ? 0 : 2048;
#pragma unroll
    for (int j = 0; j < 4; ++j) {
        const int col = n0 + wn + j * 16 + l15;
        const int cl  = col - base;
        const float bv = bp[cl];
#pragma unroll
        for (int i = 0; i < 4; ++i) {
            const int row = m0 + wm + i * 16 + quad * 4;
#pragma unroll
            for (int r = 0; r < 4; ++r)
                outp[(size_t)(row + r) * 2048 + cl] = (bf16)(acc[i][j][r] + bv);
        }
    }
}

// ---------------------------------------------------------------------------
// qC GEMM with fused RoPE epilogue: writes qC = A@Wt+b (bf16) AND
// qR = rope(qC fp32) (bf16). Pair partner col^1 lives in lane l15^1.
// __sincosf (hw v_sin/v_cos): sincosf's Payne-Hanek slow path used scratch
// -> 845 MB WRITE_SIZE (round-3 post-mortem). Angle err ~2e-4 rad << bf16.
// ---------------------------------------------------------------------------
__global__ __launch_bounds__(256, 2)
void gemm_q_rope(const bf16* __restrict__ A, const bf16* __restrict__ Bt,
                 const float* __restrict__ bias,
                 bf16* __restrict__ qC, bf16* __restrict__ qR)
{
    __shared__ bf16 As[128 * 64];
    __shared__ bf16 Bs[128 * 64];
    const int m0 = blockIdx.y * 128;
    const int n0 = blockIdx.x * 128;
    f32x4 acc[4][4] = {};
    gemm_core(A, Bt, 1536, m0, n0, As, Bs, acc);

    const int tid  = threadIdx.x;
    const int wave = tid >> 6;
    const int lane = tid & 63;
    const int quad = lane >> 4;
    const int l15  = lane & 15;
    const int wm   = (wave >> 1) * 64;
    const int wn   = (wave & 1) * 64;
    const int odd  = l15 & 1;

#pragma unroll
    for (int j = 0; j < 4; ++j) {
        const int col = n0 + wn + j * 16 + l15;
        const float bv = bias[col];
        const float freq = exp2f(-(float)((col & 127) >> 1) * INVF_C);
#pragma unroll
        for (int i = 0; i < 4; ++i) {
            const int rowb = m0 + wm + i * 16 + quad * 4;
#pragma unroll
            for (int r = 0; r < 4; ++r) {
                const int row = rowb + r;
                const float v = acc[i][j][r] + bv;
                qC[(size_t)row * 2048 + col] = (bf16)v;
                const float vp = __shfl_xor(v, 1, 64);
                const float x1 = odd ? vp : v;
                const float x2 = odd ? v  : vp;
                const float ang = (float)(row & 2047) * freq;
                float sn, cs;
                __sincosf(ang, &sn, &cs);
                qR[(size_t)row * 2048 + col] =
                    (bf16)(odd ? (x1 * sn + x2 * cs) : (x1 * cs - x2 * sn));
            }
        }
    }
}

// vC (B*S, H*128) bf16 -> vT (B*H, 128, S). grid (S/32, 128/32, 32), block (32,8)
__global__ void transpose_v(const bf16* __restrict__ vC, bf16* __restrict__ vT)
{
    __shared__ bf16 tile[32][33];
    const int bh = blockIdx.z, b = bh >> 4, h = bh & 15;
    const int s0 = blockIdx.x * 32, d0 = blockIdx.y * 32;
    const int tx = threadIdx.x, ty = threadIdx.y;
    for (int i = ty; i < 32; i += 8)
        tile[i][tx] = vC[((size_t)(b * 2048 + s0 + i)) * 2048 + h * 128 + d0 + tx];
    __syncthreads();
    for (int i = ty; i < 32; i += 8)
        vT[((size_t)(bh * 128 + d0 + i)) * 2048 + s0 + tx] = tile[tx][i];
}

// ---------------------------------------------------------------------------
// per-head interleaved RoPE (kR path), layout (B*S, H*128), fp32 input.
// __sincosf: no scratch slow path (round-3 post-mortem).
// ---------------------------------------------------------------------------
__global__ void rope_heads_f(const float* __restrict__ in, bf16* __restrict__ out)
{
    const int idx = blockIdx.x * 256 + threadIdx.x;     // 2*2048*16*64 total
    const int j = idx & 63;
    const int h = (idx >> 6) & 15;
    const int s = (idx >> 10) & 2047;
    const int b = idx >> 21;
    const size_t src = ((size_t)(b * 2048 + s)) * 2048 + h * 128 + 2 * j;
    const float x1 = in[src], x2 = in[src + 1];
    const float ang = (float)s * exp2f(-(float)j * INVF_C);
    float sn, cs;
    __sincosf(ang, &sn, &cs);
    out[src]     = (bf16)(x1 * cs - x2 * sn);
    out[src + 1] = (bf16)(x1 * sn + x2 * cs);
}

// ---------------------------------------------------------------------------
// Flash attention, causal. Split operands, all bf16:
//   qC,qR,kC,kR : (B*S, H*128) row-major;  Vt : (B*H, 128, S).
// BQ=128 (8 waves x 16 q-rows, wave-local softmax), BKV=64.
// Grid (bh=32, y=16): 512 blocks, 2/CU -> all co-resident.
// Balance remap: co-resident pair (y, y+8) -> q-tiles (2y, 15-2y) -> constant
// 34 KV-tile-units per CU (verified round 2: 159 -> 138 us).
// launch_bounds(512,2): 2 blocks/CU = what LDS allows; (512,4) caused a
// 64-VGPR cap and spills (round-1 post-mortem).
// No setprio / no defer-max: both regressed in round 5 (134 -> 147 us;
// 8-wave lockstep = m190 null case, not m191's independent-wave case).
// T14 async-stage (retry of round 0): issue t+1's global loads BEFORE
// compute(t); LDS write after the post-compute barrier. Round-1 failure
// was the 64-VGPR corset (spills); at 128-VGPR cap, 68+24 regs fit.
// LDS: Ks 64x264 + Vs 128x72 + Ps 128x72 = 70656 B.
// ---------------------------------------------------------------------------
__global__ __launch_bounds__(512, 2)
void mla_attn(const bf16* __restrict__ qCp, const bf16* __restrict__ qRp,
              const bf16* __restrict__ kCp, const bf16* __restrict__ kRp,
              const bf16* __restrict__ Vt, bf16* __restrict__ ctx)
{
    __shared__ bf16 Ks[64 * 264];
    __shared__ bf16 Vs[128 * 72];
    __shared__ bf16 Ps[128 * 72];
    const int bh   = blockIdx.x;
    const int b    = bh >> 4, hh = bh & 15;
    const int yq   = blockIdx.y;
    const int qt   = (yq < 8) ? (2 * yq) : (31 - 2 * yq);   // balance remap
    const int q0   = qt * 128;
    const int tid  = threadIdx.x;
    const int wave = tid >> 6;
    const int lane = tid & 63;
    const int quad = lane >> 4;
    const int l15  = lane & 15;
    const int wq   = q0 + wave * 16;       // wave's first q row

    // Q fragments resident (A-operand: m=lane&15, k=quad*8+j).
    bf16x8 qf[8];
    {
        const size_t qoff = ((size_t)(b * 2048 + wq + l15)) * 2048
                          + hh * 128 + quad * 8;
#pragma unroll
        for (int ks = 0; ks < 4; ++ks) {
            qf[ks]     = *(const bf16x8*)(qCp + qoff + ks * 32);
            qf[4 + ks] = *(const bf16x8*)(qRp + qoff + ks * 32);
        }
    }

    float mstate[4], lstate[4];
    f32x4 o[8];
#pragma unroll
    for (int r = 0; r < 4; ++r) { mstate[r] = -1e30f; lstate[r] = 0.0f; }
#pragma unroll
    for (int dt = 0; dt < 8; ++dt) { f32x4 z = {0.f, 0.f, 0.f, 0.f}; o[dt] = z; }

    const int krow = tid >> 4, kcol = (tid & 15) * 8;   // K staging (512 thr)
    const int vsr  = tid >> 3, vsc  = (tid & 7) * 8;    // V staging

    // T14 staging registers (6 x bf16x8 = 24 VGPR)
    bf16x8 stKC[2], stKR[2], stV[2];

    const int ntiles = 2 * qt + 2;

    // prologue: load tile 0 into regs, write LDS, sync
    {
#pragma unroll
        for (int it = 0; it < 2; ++it) {
            const int row = it * 32 + krow;
            const size_t g = ((size_t)(b * 2048 + row)) * 2048 + hh * 128 + kcol;
            stKC[it] = *(const bf16x8*)(kCp + g);
            stKR[it] = *(const bf16x8*)(kRp + g);
        }
#pragma unroll
        for (int it = 0; it < 2; ++it) {
            const int d = it * 64 + vsr;
            stV[it] = *(const bf16x8*)(Vt + ((size_t)(bh * 128 + d)) * 2048 + vsc);
        }
#pragma unroll
        for (int it = 0; it < 2; ++it) {
            const int row = it * 32 + krow;
            *(bf16x8*)&Ks[row * 264 + kcol]       = stKC[it];
            *(bf16x8*)&Ks[row * 264 + 128 + kcol] = stKR[it];
        }
#pragma unroll
        for (int it = 0; it < 2; ++it) {
            const int d = it * 64 + vsr;
            *(bf16x8*)&Vs[d * 72 + vsc] = stV[it];
        }
    }
    __syncthreads();

    for (int t = 0; t < ntiles; ++t) {
        const int kk0 = t * 64;

        // T14: issue next tile's global loads; latency hides under compute(t)
        if (t + 1 < ntiles) {
            const int nk0 = kk0 + 64;
#pragma unroll
            for (int it = 0; it < 2; ++it) {
                const int row = it * 32 + krow;
                const size_t g = ((size_t)(b * 2048 + nk0 + row)) * 2048 + hh * 128 + kcol;
                stKC[it] = *(const bf16x8*)(kCp + g);
                stKR[it] = *(const bf16x8*)(kRp + g);
            }
#pragma unroll
            for (int it = 0; it < 2; ++it) {
                const int d = it * 64 + vsr;
                stV[it] = *(const bf16x8*)(Vt + ((size_t)(bh * 128 + d)) * 2048 + nk0 + vsc);
            }
        }

        if (kk0 <= wq + 15) {   // wave-uniform: tile not fully masked
            f32x4 sc[4] = {};
#pragma unroll
            for (int ks = 0; ks < 8; ++ks)
#pragma unroll
                for (int j = 0; j < 4; ++j) {
                    bf16x8 kf = *(const bf16x8*)&Ks[(j * 16 + l15) * 264 + ks * 32 + quad * 8];
                    sc[j] = __builtin_amdgcn_mfma_f32_16x16x32_bf16(qf[ks], kf, sc[j], 0, 0, 0);
                }

            const bool diag = (kk0 + 63 > wq);
            float rowmax[4] = {-1e30f, -1e30f, -1e30f, -1e30f};
#pragma unroll
            for (int j = 0; j < 4; ++j) {
                const int kkcol = kk0 + j * 16 + l15;
#pragma unroll
                for (int r = 0; r < 4; ++r) {
                    float s = sc[j][r] * 0.0625f;             // 1/sqrt(256)
                    if (diag && (kkcol > wq + quad * 4 + r)) s = -1e30f;
                    sc[j][r] = s;
                    rowmax[r] = fmaxf(rowmax[r], s);
                }
            }
#pragma unroll
            for (int r = 0; r < 4; ++r) {  // reduce across the 16 col-lanes
                float v = rowmax[r];
                v = fmaxf(v, __shfl_xor(v, 1, 64));
                v = fmaxf(v, __shfl_xor(v, 2, 64));
                v = fmaxf(v, __shfl_xor(v, 4, 64));
                v = fmaxf(v, __shfl_xor(v, 8, 64));
                rowmax[r] = v;
            }
            float alpha[4];
#pragma unroll
            for (int r = 0; r < 4; ++r) {
                const float mnew = fmaxf(mstate[r], rowmax[r]);
                alpha[r] = __expf(mstate[r] - mnew);
                mstate[r] = mnew;
            }
            float rowsum[4] = {0.f, 0.f, 0.f, 0.f};
#pragma unroll
            for (int j = 0; j < 4; ++j)
#pragma unroll
                for (int r = 0; r < 4; ++r) {
                    const float p = __expf(sc[j][r] - mstate[r]);
                    sc[j][r] = p;
                    rowsum[r] += p;
                }
#pragma unroll
            for (int r = 0; r < 4; ++r) {
                float v = rowsum[r];
                v += __shfl_xor(v, 1, 64);
                v += __shfl_xor(v, 2, 64);
                v += __shfl_xor(v, 4, 64);
                v += __shfl_xor(v, 8, 64);
                lstate[r] = lstate[r] * alpha[r] + v;
            }
            // P: C-layout -> LDS -> A-operand layout (verified, m120)
#pragma unroll
            for (int j = 0; j < 4; ++j)
#pragma unroll
                for (int r = 0; r < 4; ++r)
                    Ps[(wave * 16 + quad * 4 + r) * 72 + j * 16 + l15] = (bf16)sc[j][r];
#pragma unroll
            for (int dt = 0; dt < 8; ++dt)
#pragma unroll
                for (int r = 0; r < 4; ++r)
                    o[dt][r] *= alpha[r];
#pragma unroll
            for (int ks2 = 0; ks2 < 2; ++ks2) {
                bf16x8 pf = *(const bf16x8*)&Ps[(wave * 16 + l15) * 72 + ks2 * 32 + quad * 8];
#pragma unroll
                for (int dt = 0; dt < 8; ++dt) {
                    bf16x8 vf = *(const bf16x8*)&Vs[(dt * 16 + l15) * 72 + ks2 * 32 + quad * 8];
                    o[dt] = __builtin_amdgcn_mfma_f32_16x16x32_bf16(pf, vf, o[dt], 0, 0, 0);
                }
            }
        }

        __syncthreads();   // everyone done reading Ks/Vs of tile t
        if (t + 1 < ntiles) {
            // T14: LDS write of the prefetched tile (vmcnt drained on use)
#pragma unroll
            for (int it = 0; it < 2; ++it) {
                const int row = it * 32 + krow;
                *(bf16x8*)&Ks[row * 264 + kcol]       = stKC[it];
                *(bf16x8*)&Ks[row * 264 + 128 + kcol] = stKR[it];
            }
#pragma unroll
            for (int it = 0; it < 2; ++it) {
                const int d = it * 64 + vsr;
                *(bf16x8*)&Vs[d * 72 + vsc] = stV[it];
            }
        }
        __syncthreads();   // staged data visible for tile t+1
    }

    float inv_l[4];
#pragma unroll
    for (int r = 0; r < 4; ++r) inv_l[r] = 1.0f / lstate[r];
#pragma unroll
    for (int dt = 0; dt < 8; ++dt) {
        const int d = dt * 16 + l15;
#pragma unroll
        for (int r = 0; r < 4; ++r) {
            const int q = wq + quad * 4 + r;
            ctx[((size_t)(b * 2048 + q)) * 2048 + hh * 128 + d] = (bf16)(o[dt][r] * inv_l[r]);
        }
    }
}

// ---------------------------------------------------------------------------
extern "C" void kernel_launch(void* const* d_in, const int* in_sizes, int n_in,
                              void* d_out, int out_size, void* d_ws, size_t ws_size,
                              hipStream_t stream)
{
    const float* h     = (const float*)d_in[0];
    const float* W_DKV = (const float*)d_in[1];
    const float* b_DKV = (const float*)d_in[2];
    const float* W_UK  = (const float*)d_in[3];
    const float* b_UK  = (const float*)d_in[4];
    const float* W_UV  = (const float*)d_in[5];
    const float* b_UV  = (const float*)d_in[6];
    const float* W_DQ  = (const float*)d_in[7];
    const float* b_DQ  = (const float*)d_in[8];
    const float* W_UQ  = (const float*)d_in[9];
    const float* b_UQ  = (const float*)d_in[10];
    const float* W_KR  = (const float*)d_in[11];
    const float* b_KR  = (const float*)d_in[12];
    const float* W_O   = (const float*)d_in[13];
    const float* b_O   = (const float*)d_in[14];

    float* out   = (float*)d_out;             // (4096, 2048)  output 0, fp32
    float* cKV_f = out + (size_t)8388608;     // (4096, 512)   output 1
    float* krc_f = out + (size_t)10485760;    // (4096, 2048)  output 2

    // out-proper (33.5 MB) is dead until the final GEMM -> park qC + qR
    // there; both consumed by mla_attn before the final GEMM overwrites.
    bf16* qC = (bf16*)d_out;                  // (B*S, H*128)
    bf16* qR = (bf16*)d_out + 8388608;        // (B*S, H*128)

    // ws (bf16 elements), lifetimes:
    //  hb    @0        8.4M  cast -> batch1; then reused as kR
    //  cKVb  @8.4M     2.1M  batch1 -> batch45
    //  cQ    @10.5M    6.3M  batch1 -> gemm_q
    //  WtAll @16.8M    8.4M  tc(DKV|KR|DQ) -> batch1; tc(UK|UV) -> batch45;
    //                        tc(UQ) -> gemm_q; then vT -> attn; then tc(WO)
    //  kC    @25.2M    8.4M  batch45 -> attn
    //  vC    @33.6M    8.4M  batch45 -> transpose_v; then ctx (attn -> final)
    bf16* ws    = (bf16*)d_ws;
    bf16* hb    = ws + 0;
    bf16* cKVb  = ws + 8388608;
    bf16* cQ    = ws + 10485760;
    bf16* WtAll = ws + 16777216;
    bf16* kC    = ws + 25165824;
    bf16* vC    = ws + 33554432;
    bf16* kR    = hb;              // hb dead after batch1
    bf16* vT    = WtAll;           // WtAll free between gemm_q and tc(WO)
    bf16* ctx   = vC;              // vC dead after transpose_v

    dim3 tb(32, 8);

    cast_to_bf16<<<8192, 256, 0, stream>>>(h, hb, 8388608);

    // WtAll rows: [0,512)=W_DKV^T, [512,2560)=W_KR^T, [2560,4096)=W_DQ^T
    transpose_cast<<<dim3(16, 64), tb, 0, stream>>>(W_DKV, WtAll,           2048, 512);
    transpose_cast<<<dim3(64, 64), tb, 0, stream>>>(W_KR,  WtAll + 1048576, 2048, 2048);
    transpose_cast<<<dim3(48, 64), tb, 0, stream>>>(W_DQ,  WtAll + 5242880, 2048, 1536);

    gemm_batch1<<<dim3(32, 32), 256, 0, stream>>>(hb, WtAll, b_DKV, b_KR, b_DQ,
                                                  cKV_f, cKVb, krc_f, cQ);
    // hb dead from here
    rope_heads_f<<<16384, 256, 0, stream>>>(krc_f, kR);

    // Wt45 rows: [0,2048)=W_UK^T, [2048,4096)=W_UV^T (K=512)
    transpose_cast<<<dim3(64, 16), tb, 0, stream>>>(W_UK, WtAll,           512, 2048);
    transpose_cast<<<dim3(64, 16), tb, 0, stream>>>(W_UV, WtAll + 1048576, 512, 2048);
    gemm_batch45<<<dim3(32, 32), 256, 0, stream>>>(cKVb, WtAll, b_UK, b_UV, kC, vC);

    transpose_cast<<<dim3(64, 48), tb, 0, stream>>>(W_UQ, WtAll, 1536, 2048);
    gemm_q_rope<<<dim3(16, 32), 256, 0, stream>>>(cQ, WtAll, b_UQ, qC, qR);

    transpose_v<<<dim3(64, 4, 32), tb, 0, stream>>>(vC, vT);   // vC consumed

    mla_attn<<<dim3(32, 16), 512, 0, stream>>>(qC, qR, kC, kR, vT, ctx);

    transpose_cast<<<dim3(64, 64), tb, 0, stream>>>(W_O, WtAll, 2048, 2048);
    gemm_bt<<<dim3(16, 32), 256, 0, stream>>>(ctx, WtAll, b_O, out, nullptr, 4096, 2048, 2048);
}